// Round 2
// baseline (323.246 us; speedup 1.0000x reference)
//
#include <hip/hip_runtime.h>
#include <hip/hip_bf16.h>
#include <cstdint>

#define N_NODES 4096
#define IN_FEAT 256
#define OUT_FEAT 64
#define NHEAD 8
#define LOG2E 1.4426950408889634f

typedef __bf16 bf16x8 __attribute__((ext_vector_type(8)));
typedef float  f32x4  __attribute__((ext_vector_type(4)));

// ---------------------------------------------------------------------------
// Phase 1: per-head projection h = x @ W[h]   (4096x256 @ 256x64)
// Inputs f32; MFMA in bf16 (inputs cast in-register). Outputs:
//   h_t  [8][64][4096] bf16  (transposed: phase-2 B-fragments = contiguous 16B)
//   srcp [8][4096] f32 = (h . a_src) * log2(e)
//   dstp [8][4096] f32 = (h . a_dst) * log2(e)
// Grid: 512 blocks x 256 thr (4 waves). wave -> (head, 16-row tile).
// ---------------------------------------------------------------------------
__global__ __launch_bounds__(256) void gat_phase1(
    const float* __restrict__ x,      // [4096][256] f32
    const float* __restrict__ W,      // [8][256][64] f32
    const float* __restrict__ a,      // [8][128] f32
    __bf16* __restrict__ h_t,
    float*  __restrict__ srcp,
    float*  __restrict__ dstp)
{
    const int lane = threadIdx.x & 63;
    const int wv   = threadIdx.x >> 6;
    const int gw   = blockIdx.x * 4 + wv;   // 0..2047
    const int hd   = gw & 7;
    const int tile = gw >> 3;               // 0..255 (16-row tiles)
    const int r    = lane & 15;
    const int q    = lane >> 4;
    const int nb   = tile * 16;

    const float* Wg   = W + (size_t)hd * (IN_FEAT * OUT_FEAT);
    const float* xrow = x + (size_t)(nb + r) * IN_FEAT;

    f32x4 acc[4] = {};  // acc[f][reg] = h[nb + 4q + reg][16f + r]

    for (int k0 = 0; k0 < IN_FEAT; k0 += 32) {
        float4 xa = *(const float4*)(xrow + k0 + q * 8);
        float4 xb = *(const float4*)(xrow + k0 + q * 8 + 4);
        bf16x8 af;  // A[m=r][k=q*8+j]
        af[0] = (__bf16)xa.x; af[1] = (__bf16)xa.y;
        af[2] = (__bf16)xa.z; af[3] = (__bf16)xa.w;
        af[4] = (__bf16)xb.x; af[5] = (__bf16)xb.y;
        af[6] = (__bf16)xb.z; af[7] = (__bf16)xb.w;
        #pragma unroll
        for (int f = 0; f < 4; ++f) {
            bf16x8 bf;
            #pragma unroll
            for (int j = 0; j < 8; ++j)   // B[k=q*8+j][n=r] (col 16f+r)
                bf[j] = (__bf16)Wg[(size_t)(k0 + q * 8 + j) * OUT_FEAT + 16 * f + r];
            acc[f] = __builtin_amdgcn_mfma_f32_16x16x32_bf16(af, bf, acc[f], 0, 0, 0);
        }
    }

    // attention projections from f32 accumulators
    float asv[4], adv[4];
    #pragma unroll
    for (int f = 0; f < 4; ++f) {
        asv[f] = a[hd * 128 + 16 * f + r];
        adv[f] = a[hd * 128 + 64 + 16 * f + r];
    }
    float sp[4], dp[4];
    #pragma unroll
    for (int reg = 0; reg < 4; ++reg) {
        sp[reg] = acc[0][reg] * asv[0] + acc[1][reg] * asv[1]
                + acc[2][reg] * asv[2] + acc[3][reg] * asv[3];
        dp[reg] = acc[0][reg] * adv[0] + acc[1][reg] * adv[1]
                + acc[2][reg] * adv[2] + acc[3][reg] * adv[3];
    }
    #pragma unroll
    for (int m = 1; m <= 8; m <<= 1) {
        #pragma unroll
        for (int reg = 0; reg < 4; ++reg) {
            sp[reg] += __shfl_xor(sp[reg], m);
            dp[reg] += __shfl_xor(dp[reg], m);
        }
    }

    // store transposed h (bf16)
    #pragma unroll
    for (int f = 0; f < 4; ++f)
        #pragma unroll
        for (int reg = 0; reg < 4; ++reg)
            h_t[(size_t)(hd * OUT_FEAT + 16 * f + r) * N_NODES + nb + 4 * q + reg] =
                (__bf16)acc[f][reg];

    if (r == 0) {
        #pragma unroll
        for (int reg = 0; reg < 4; ++reg) {
            int row = nb + 4 * q + reg;
            srcp[hd * N_NODES + row] = sp[reg] * LOG2E;
            dstp[hd * N_NODES + row] = dp[reg] * LOG2E;
        }
    }
}

// ---------------------------------------------------------------------------
// Phase 2: masked softmax aggregation + head-mean + ELU.
// Grid: 256 blocks (16 rows each) x 512 thr (8 waves; wave = head).
// w[n][m] = adj ? exp2(lrelu(src'[n] + dst'[m])) : 0   (log2-domain lrelu:
// max(t,0.2t) commutes with the positive log2(e) pre-scale)
// num cols 0..47 in acc[0..2], den (ones-MFMA) in acc[3], cols 48..63 in accd.
// out = elu(mean_h(num/den)), f32.
// ---------------------------------------------------------------------------
__global__ __launch_bounds__(512) void gat_phase2(
    const __bf16* __restrict__ h_t,
    const float*  __restrict__ srcp,
    const float*  __restrict__ dstp,
    const int*    __restrict__ adj,
    float* __restrict__ out)
{
    const int lane = threadIdx.x & 63;
    const int hd   = threadIdx.x >> 6;
    const int r    = lane & 15;
    const int q    = lane >> 4;
    const int n0   = blockIdx.x * 16;

    __shared__ float num_s[NHEAD][16][64];

    const float   srcv   = srcp[hd * N_NODES + n0 + r];
    const float*  dsth   = dstp + hd * N_NODES;
    const __bf16* Vh     = h_t + (size_t)hd * OUT_FEAT * N_NODES;
    const int*    adjrow = adj + (size_t)(n0 + r) * N_NODES;

    f32x4 acc[4] = {};   // acc[0..2]: num cols 0..47; acc[3]: den (ones column)
    f32x4 accd   = {};   // num cols 48..63
    bf16x8 ones;
    #pragma unroll
    for (int j = 0; j < 8; ++j) ones[j] = (__bf16)1.0f;

    for (int m0 = 0; m0 < N_NODES; m0 += 32) {
        const int mq = m0 + q * 8;
        float4 d0 = *(const float4*)(dsth + mq);
        float4 d1 = *(const float4*)(dsth + mq + 4);
        int4   A0 = *(const int4*)(adjrow + mq);
        int4   A1 = *(const int4*)(adjrow + mq + 4);
        float dv[8] = {d0.x, d0.y, d0.z, d0.w, d1.x, d1.y, d1.z, d1.w};
        int   av[8] = {A0.x, A0.y, A0.z, A0.w, A1.x, A1.y, A1.z, A1.w};

        bf16x8 af;   // A[m=r][k=q*8+j] = w[n0+r][mq+j]
        #pragma unroll
        for (int j = 0; j < 8; ++j) {
            float t = srcv + dv[j];            // (src+dst)*log2e
            float e = fmaxf(t, 0.2f * t);      // leaky_relu in log2 domain
            float wvv = av[j] ? exp2f(e) : 0.0f;
            af[j] = (__bf16)wvv;
        }

        bf16x8 b0 = *(const bf16x8*)(Vh + (size_t)(r)      * N_NODES + mq);
        bf16x8 b1 = *(const bf16x8*)(Vh + (size_t)(16 + r) * N_NODES + mq);
        bf16x8 b2 = *(const bf16x8*)(Vh + (size_t)(32 + r) * N_NODES + mq);
        bf16x8 b3 = *(const bf16x8*)(Vh + (size_t)(48 + r) * N_NODES + mq);

        acc[0] = __builtin_amdgcn_mfma_f32_16x16x32_bf16(af, b0,   acc[0], 0, 0, 0);
        acc[1] = __builtin_amdgcn_mfma_f32_16x16x32_bf16(af, b1,   acc[1], 0, 0, 0);
        acc[2] = __builtin_amdgcn_mfma_f32_16x16x32_bf16(af, b2,   acc[2], 0, 0, 0);
        acc[3] = __builtin_amdgcn_mfma_f32_16x16x32_bf16(af, ones, acc[3], 0, 0, 0);
        accd   = __builtin_amdgcn_mfma_f32_16x16x32_bf16(af, b3,   accd,   0, 0, 0);
    }

    // scale: num/(8*den); acc[3] holds den (every column identical)
    #pragma unroll
    for (int reg = 0; reg < 4; ++reg) {
        float inv = 0.125f / acc[3][reg];
        num_s[hd][4 * q + reg][ 0 + r] = acc[0][reg] * inv;
        num_s[hd][4 * q + reg][16 + r] = acc[1][reg] * inv;
        num_s[hd][4 * q + reg][32 + r] = acc[2][reg] * inv;
        num_s[hd][4 * q + reg][48 + r] = accd[reg]   * inv;
    }
    __syncthreads();

    // head-mean + ELU + f32 store (2 outputs / thread)
    {
        int idx = threadIdx.x * 2;   // 0..1022
        int rr  = idx >> 6;
        int o   = idx & 63;
        float s0 = 0.f, s1 = 0.f;
        #pragma unroll
        for (int h2 = 0; h2 < NHEAD; ++h2) {
            s0 += num_s[h2][rr][o];
            s1 += num_s[h2][rr][o + 1];
        }
        float e0 = s0 > 0.f ? s0 : expm1f(s0);
        float e1 = s1 > 0.f ? s1 : expm1f(s1);
        float2 pk = {e0, e1};
        *(float2*)(out + (size_t)(n0 + rr) * OUT_FEAT + o) = pk;
    }
}

// ---------------------------------------------------------------------------
extern "C" void kernel_launch(void* const* d_in, const int* in_sizes, int n_in,
                              void* d_out, int out_size, void* d_ws, size_t ws_size,
                              hipStream_t stream)
{
    const float* x   = (const float*)d_in[0];
    const int*   adj = (const int*)d_in[1];
    const float* W   = (const float*)d_in[2];
    const float* a   = (const float*)d_in[3];
    float* out = (float*)d_out;

    char* ws = (char*)d_ws;
    __bf16* h_t  = (__bf16*)ws;                                            // 4 MB
    float*  srcp = (float*)(ws + (size_t)NHEAD * OUT_FEAT * N_NODES * 2);  // 128 KB
    float*  dstp = srcp + NHEAD * N_NODES;                                 // 128 KB

    gat_phase1<<<512, 256, 0, stream>>>(x, W, a, h_t, srcp, dstp);
    gat_phase2<<<256, 512, 0, stream>>>(h_t, srcp, dstp, adj, out);
}

// Round 3
// 312.272 us; speedup vs baseline: 1.0351x; 1.0351x over previous
//
#include <hip/hip_runtime.h>
#include <hip/hip_bf16.h>
#include <cstdint>

#define N_NODES 4096
#define IN_FEAT 256
#define OUT_FEAT 64
#define NHEAD 8
#define LOG2E 1.4426950408889634f

typedef __bf16 bf16x8 __attribute__((ext_vector_type(8)));
typedef float  f32x4  __attribute__((ext_vector_type(4)));

// ws layout (bytes):
//   h_t   @ 0        : 8*64*4096*2   = 4194304   bf16, transposed per-head V
//   srcp  @ 4194304  : 8*4096*4      = 131072    f32
//   dstp  @ 4325376  : 8*4096*4      = 131072    f32
//   Wt    @ 4456448  : 8*64*256*2    = 262144    bf16, W transposed [h][col][k]
//   numP  @ 4718592  : C*256*8*16*64*4 = C*8388608  f32 partial numerators
//   denP  @ 4718592 + C*8388608 : C*256*8*16*4 = C*131072
#define OFF_SRCP 4194304
#define OFF_DSTP 4325376
#define OFF_WT   4456448
#define OFF_NUMP 4718592
#define NUMP_CHUNK_BYTES 8388608ULL
#define DENP_CHUNK_BYTES 131072ULL

// ---------------------------------------------------------------------------
// Prepack: Wt[hd][col][k] = (bf16) W[hd][k][col]. 16384 threads, 8 k's each.
// ---------------------------------------------------------------------------
__global__ __launch_bounds__(256) void gat_prepack(
    const float* __restrict__ W, __bf16* __restrict__ Wt)
{
    int gid = blockIdx.x * 256 + threadIdx.x;   // 0..16383
    int hd  = gid >> 11;
    int rem = gid & 2047;
    int c   = rem >> 5;        // 0..63
    int kg  = rem & 31;        // 0..31 (groups of 8 k)
    const float* src = W + ((size_t)hd * IN_FEAT + kg * 8) * OUT_FEAT + c;
    bf16x8 v;
    #pragma unroll
    for (int t = 0; t < 8; ++t) v[t] = (__bf16)src[(size_t)t * OUT_FEAT];
    *(bf16x8*)(Wt + ((size_t)hd * OUT_FEAT + c) * IN_FEAT + kg * 8) = v;
}

// ---------------------------------------------------------------------------
// Phase 1: h = x @ W[h] via bf16 MFMA; emits h_t (transposed bf16) + src/dst
// projections (pre-scaled by log2 e). Grid: 512 x 256 (wave = head,16-rows).
// ---------------------------------------------------------------------------
__global__ __launch_bounds__(256) void gat_phase1(
    const float*  __restrict__ x,      // [4096][256] f32
    const __bf16* __restrict__ Wt,     // [8][64][256] bf16
    const float*  __restrict__ a,      // [8][128] f32
    __bf16* __restrict__ h_t,
    float*  __restrict__ srcp,
    float*  __restrict__ dstp)
{
    const int lane = threadIdx.x & 63;
    const int wv   = threadIdx.x >> 6;
    const int gw   = blockIdx.x * 4 + wv;   // 0..2047
    const int hd   = gw & 7;
    const int tile = gw >> 3;               // 0..255
    const int r    = lane & 15;
    const int q    = lane >> 4;
    const int nb   = tile * 16;

    const float*  xrow = x  + (size_t)(nb + r) * IN_FEAT;
    const __bf16* Wth  = Wt + (size_t)hd * OUT_FEAT * IN_FEAT;

    f32x4 acc[4] = {};  // acc[f][reg] = h[nb + 4q + reg][16f + r]

    #pragma unroll
    for (int k0 = 0; k0 < IN_FEAT; k0 += 32) {
        float4 xa = *(const float4*)(xrow + k0 + q * 8);
        float4 xb = *(const float4*)(xrow + k0 + q * 8 + 4);
        bf16x8 af;  // A[m=r][k=q*8+j]
        af[0] = (__bf16)xa.x; af[1] = (__bf16)xa.y;
        af[2] = (__bf16)xa.z; af[3] = (__bf16)xa.w;
        af[4] = (__bf16)xb.x; af[5] = (__bf16)xb.y;
        af[6] = (__bf16)xb.z; af[7] = (__bf16)xb.w;
        #pragma unroll
        for (int f = 0; f < 4; ++f) {
            // B[k=q*8+j][col=16f+r] — contiguous 16B in Wt
            bf16x8 bf = *(const bf16x8*)(Wth + (size_t)(16 * f + r) * IN_FEAT + k0 + q * 8);
            acc[f] = __builtin_amdgcn_mfma_f32_16x16x32_bf16(af, bf, acc[f], 0, 0, 0);
        }
    }

    float asv[4], adv[4];
    #pragma unroll
    for (int f = 0; f < 4; ++f) {
        asv[f] = a[hd * 128 + 16 * f + r];
        adv[f] = a[hd * 128 + 64 + 16 * f + r];
    }
    float sp[4], dp[4];
    #pragma unroll
    for (int reg = 0; reg < 4; ++reg) {
        sp[reg] = acc[0][reg] * asv[0] + acc[1][reg] * asv[1]
                + acc[2][reg] * asv[2] + acc[3][reg] * asv[3];
        dp[reg] = acc[0][reg] * adv[0] + acc[1][reg] * adv[1]
                + acc[2][reg] * adv[2] + acc[3][reg] * adv[3];
    }
    #pragma unroll
    for (int m = 1; m <= 8; m <<= 1) {
        #pragma unroll
        for (int reg = 0; reg < 4; ++reg) {
            sp[reg] += __shfl_xor(sp[reg], m);
            dp[reg] += __shfl_xor(dp[reg], m);
        }
    }

    #pragma unroll
    for (int f = 0; f < 4; ++f)
        #pragma unroll
        for (int reg = 0; reg < 4; ++reg)
            h_t[(size_t)(hd * OUT_FEAT + 16 * f + r) * N_NODES + nb + 4 * q + reg] =
                (__bf16)acc[f][reg];

    if (r == 0) {
        #pragma unroll
        for (int reg = 0; reg < 4; ++reg) {
            int row = nb + 4 * q + reg;
            srcp[hd * N_NODES + row] = sp[reg] * LOG2E;
            dstp[hd * N_NODES + row] = dp[reg] * LOG2E;
        }
    }
}

// ---------------------------------------------------------------------------
// Phase 2 (partial): block = (chunk, rowblk), 512 thr (wave = head).
// Computes UNNORMALIZED partial num (16x64) + partial den over its m-chunk.
// ---------------------------------------------------------------------------
__global__ __launch_bounds__(512) void gat_phase2p(
    const __bf16* __restrict__ h_t,
    const float*  __restrict__ srcp,
    const float*  __restrict__ dstp,
    const int*    __restrict__ adj,
    float* __restrict__ numP,
    float* __restrict__ denP,
    int mlen)
{
    const int lane   = threadIdx.x & 63;
    const int hd     = threadIdx.x >> 6;
    const int r      = lane & 15;
    const int q      = lane >> 4;
    const int rowblk = blockIdx.x & 255;
    const int chunk  = blockIdx.x >> 8;
    const int n0     = rowblk * 16;
    const int mbase  = chunk * mlen;

    const float   srcv   = srcp[hd * N_NODES + n0 + r];
    const float*  dsth   = dstp + (size_t)hd * N_NODES + mbase;
    const __bf16* Vh     = h_t + (size_t)hd * OUT_FEAT * N_NODES + mbase;
    const int*    adjrow = adj + (size_t)(n0 + r) * N_NODES + mbase;

    f32x4 acc[4] = {};   // acc[0..2]: num cols 0..47; acc[3]: den
    f32x4 accd   = {};   // num cols 48..63
    bf16x8 ones;
    #pragma unroll
    for (int j = 0; j < 8; ++j) ones[j] = (__bf16)1.0f;

    for (int m0 = 0; m0 < mlen; m0 += 32) {
        const int mq = m0 + q * 8;
        float4 d0 = *(const float4*)(dsth + mq);
        float4 d1 = *(const float4*)(dsth + mq + 4);
        int4   A0 = *(const int4*)(adjrow + mq);
        int4   A1 = *(const int4*)(adjrow + mq + 4);
        float dv[8] = {d0.x, d0.y, d0.z, d0.w, d1.x, d1.y, d1.z, d1.w};
        int   av[8] = {A0.x, A0.y, A0.z, A0.w, A1.x, A1.y, A1.z, A1.w};

        bf16x8 af;   // A[m=r][k=q*8+j] = w[n0+r][mbase+mq+j]
        #pragma unroll
        for (int j = 0; j < 8; ++j) {
            float t = srcv + dv[j];            // (src+dst)*log2e
            float e = fmaxf(t, 0.2f * t);      // leaky_relu (log2 domain)
            float wvv = av[j] ? exp2f(e) : 0.0f;
            af[j] = (__bf16)wvv;
        }

        bf16x8 b0 = *(const bf16x8*)(Vh + (size_t)(r)      * N_NODES + mq);
        bf16x8 b1 = *(const bf16x8*)(Vh + (size_t)(16 + r) * N_NODES + mq);
        bf16x8 b2 = *(const bf16x8*)(Vh + (size_t)(32 + r) * N_NODES + mq);
        bf16x8 b3 = *(const bf16x8*)(Vh + (size_t)(48 + r) * N_NODES + mq);

        acc[0] = __builtin_amdgcn_mfma_f32_16x16x32_bf16(af, b0,   acc[0], 0, 0, 0);
        acc[1] = __builtin_amdgcn_mfma_f32_16x16x32_bf16(af, b1,   acc[1], 0, 0, 0);
        acc[2] = __builtin_amdgcn_mfma_f32_16x16x32_bf16(af, b2,   acc[2], 0, 0, 0);
        acc[3] = __builtin_amdgcn_mfma_f32_16x16x32_bf16(af, ones, acc[3], 0, 0, 0);
        accd   = __builtin_amdgcn_mfma_f32_16x16x32_bf16(af, b3,   accd,   0, 0, 0);
    }

    float* np = numP + (((size_t)(chunk * 256 + rowblk)) * NHEAD + hd) * (16 * 64);
    #pragma unroll
    for (int reg = 0; reg < 4; ++reg) {
        int row = 4 * q + reg;
        np[row * 64 +  0 + r] = acc[0][reg];
        np[row * 64 + 16 + r] = acc[1][reg];
        np[row * 64 + 32 + r] = acc[2][reg];
        np[row * 64 + 48 + r] = accd[reg];
        if (r == 0)
            denP[(((size_t)(chunk * 256 + rowblk)) * NHEAD + hd) * 16 + row] = acc[3][reg];
    }
}

// ---------------------------------------------------------------------------
// Combine: sum chunks, divide by den, mean over heads, ELU. 512 x 256.
// Block covers 8 rows; thread = (local row, col pair).
// ---------------------------------------------------------------------------
__global__ __launch_bounds__(256) void gat_combine(
    const float* __restrict__ numP,
    const float* __restrict__ denP,
    float* __restrict__ out, int C)
{
    const int tid  = threadIdx.x;
    const int lr   = tid >> 5;             // 0..7
    const int cp   = (tid & 31) * 2;       // col pair
    const int row  = blockIdx.x * 8 + lr;
    const int rb   = row >> 4;
    const int rr   = row & 15;

    float s0 = 0.f, s1 = 0.f;
    #pragma unroll
    for (int h = 0; h < NHEAD; ++h) {
        float n0 = 0.f, n1 = 0.f, den = 0.f;
        for (int c = 0; c < C; ++c) {
            size_t base = ((size_t)(c * 256 + rb)) * NHEAD + h;
            float2 v = *(const float2*)(numP + base * (16 * 64) + rr * 64 + cp);
            n0 += v.x; n1 += v.y;
            den += denP[base * 16 + rr];
        }
        float inv = 1.f / den;
        s0 += n0 * inv;
        s1 += n1 * inv;
    }
    s0 *= 0.125f; s1 *= 0.125f;
    float e0 = s0 > 0.f ? s0 : expm1f(s0);
    float e1 = s1 > 0.f ? s1 : expm1f(s1);
    float2 pk = {e0, e1};
    *(float2*)(out + (size_t)row * OUT_FEAT + cp) = pk;
}

// ---------------------------------------------------------------------------
// Fallback fused phase 2 (round-2 path) for small ws_size.
// ---------------------------------------------------------------------------
__global__ __launch_bounds__(512) void gat_phase2_fused(
    const __bf16* __restrict__ h_t,
    const float*  __restrict__ srcp,
    const float*  __restrict__ dstp,
    const int*    __restrict__ adj,
    float* __restrict__ out)
{
    const int lane = threadIdx.x & 63;
    const int hd   = threadIdx.x >> 6;
    const int r    = lane & 15;
    const int q    = lane >> 4;
    const int n0   = blockIdx.x * 16;

    __shared__ float num_s[NHEAD][16][64];

    const float   srcv   = srcp[hd * N_NODES + n0 + r];
    const float*  dsth   = dstp + (size_t)hd * N_NODES;
    const __bf16* Vh     = h_t + (size_t)hd * OUT_FEAT * N_NODES;
    const int*    adjrow = adj + (size_t)(n0 + r) * N_NODES;

    f32x4 acc[4] = {};
    f32x4 accd   = {};
    bf16x8 ones;
    #pragma unroll
    for (int j = 0; j < 8; ++j) ones[j] = (__bf16)1.0f;

    for (int m0 = 0; m0 < N_NODES; m0 += 32) {
        const int mq = m0 + q * 8;
        float4 d0 = *(const float4*)(dsth + mq);
        float4 d1 = *(const float4*)(dsth + mq + 4);
        int4   A0 = *(const int4*)(adjrow + mq);
        int4   A1 = *(const int4*)(adjrow + mq + 4);
        float dv[8] = {d0.x, d0.y, d0.z, d0.w, d1.x, d1.y, d1.z, d1.w};
        int   av[8] = {A0.x, A0.y, A0.z, A0.w, A1.x, A1.y, A1.z, A1.w};
        bf16x8 af;
        #pragma unroll
        for (int j = 0; j < 8; ++j) {
            float t = srcv + dv[j];
            float e = fmaxf(t, 0.2f * t);
            float wvv = av[j] ? exp2f(e) : 0.0f;
            af[j] = (__bf16)wvv;
        }
        bf16x8 b0 = *(const bf16x8*)(Vh + (size_t)(r)      * N_NODES + mq);
        bf16x8 b1 = *(const bf16x8*)(Vh + (size_t)(16 + r) * N_NODES + mq);
        bf16x8 b2 = *(const bf16x8*)(Vh + (size_t)(32 + r) * N_NODES + mq);
        bf16x8 b3 = *(const bf16x8*)(Vh + (size_t)(48 + r) * N_NODES + mq);
        acc[0] = __builtin_amdgcn_mfma_f32_16x16x32_bf16(af, b0,   acc[0], 0, 0, 0);
        acc[1] = __builtin_amdgcn_mfma_f32_16x16x32_bf16(af, b1,   acc[1], 0, 0, 0);
        acc[2] = __builtin_amdgcn_mfma_f32_16x16x32_bf16(af, b2,   acc[2], 0, 0, 0);
        acc[3] = __builtin_amdgcn_mfma_f32_16x16x32_bf16(af, ones, acc[3], 0, 0, 0);
        accd   = __builtin_amdgcn_mfma_f32_16x16x32_bf16(af, b3,   accd,   0, 0, 0);
    }

    #pragma unroll
    for (int reg = 0; reg < 4; ++reg) {
        float inv = 0.125f / acc[3][reg];
        num_s[hd][4 * q + reg][ 0 + r] = acc[0][reg] * inv;
        num_s[hd][4 * q + reg][16 + r] = acc[1][reg] * inv;
        num_s[hd][4 * q + reg][32 + r] = acc[2][reg] * inv;
        num_s[hd][4 * q + reg][48 + r] = accd[reg]   * inv;
    }
    __syncthreads();

    {
        int idx = threadIdx.x * 2;
        int rr  = idx >> 6;
        int o   = idx & 63;
        float s0 = 0.f, s1 = 0.f;
        #pragma unroll
        for (int h2 = 0; h2 < NHEAD; ++h2) {
            s0 += num_s[h2][rr][o];
            s1 += num_s[h2][rr][o + 1];
        }
        float e0 = s0 > 0.f ? s0 : expm1f(s0);
        float e1 = s1 > 0.f ? s1 : expm1f(s1);
        float2 pk = {e0, e1};
        *(float2*)(out + (size_t)(n0 + rr) * OUT_FEAT + o) = pk;
    }
}

// ---------------------------------------------------------------------------
extern "C" void kernel_launch(void* const* d_in, const int* in_sizes, int n_in,
                              void* d_out, int out_size, void* d_ws, size_t ws_size,
                              hipStream_t stream)
{
    const float* x   = (const float*)d_in[0];
    const int*   adj = (const int*)d_in[1];
    const float* W   = (const float*)d_in[2];
    const float* a   = (const float*)d_in[3];
    float* out = (float*)d_out;

    char* ws = (char*)d_ws;
    __bf16* h_t  = (__bf16*)ws;
    float*  srcp = (float*)(ws + OFF_SRCP);
    float*  dstp = (float*)(ws + OFF_DSTP);
    __bf16* Wt   = (__bf16*)(ws + OFF_WT);
    float*  numP = (float*)(ws + OFF_NUMP);

    // choose m-split factor by available scratch (constant per run)
    int C = 0;
    if (ws_size >= OFF_NUMP + 4 * (NUMP_CHUNK_BYTES + DENP_CHUNK_BYTES)) C = 4;
    else if (ws_size >= OFF_NUMP + 2 * (NUMP_CHUNK_BYTES + DENP_CHUNK_BYTES)) C = 2;

    gat_prepack<<<64, 256, 0, stream>>>(W, Wt);
    gat_phase1 <<<512, 256, 0, stream>>>(x, Wt, a, h_t, srcp, dstp);

    if (C) {
        float* denP = (float*)(ws + OFF_NUMP + (size_t)C * NUMP_CHUNK_BYTES);
        gat_phase2p<<<C * 256, 512, 0, stream>>>(h_t, srcp, dstp, adj, numP, denP,
                                                 N_NODES / C);
        gat_combine<<<512, 256, 0, stream>>>(numP, denP, out, C);
    } else {
        gat_phase2_fused<<<256, 512, 0, stream>>>(h_t, srcp, dstp, adj, out);
    }
}

// Round 4
// 240.851 us; speedup vs baseline: 1.3421x; 1.2965x over previous
//
#include <hip/hip_runtime.h>
#include <hip/hip_bf16.h>
#include <cstdint>

#define N_NODES 4096
#define IN_FEAT 256
#define OUT_FEAT 64
#define NHEAD 8
#define LOG2E 1.4426950408889634f

typedef __bf16 bf16x8 __attribute__((ext_vector_type(8)));
typedef float  f32x4  __attribute__((ext_vector_type(4)));

// ws layout (bytes):
//   h_t   @ 0        : 8*64*4096*2 = 4194304   bf16, transposed per-head V
//   srcp  @ 4194304  : 8*4096*4    = 131072
//   dstp  @ 4325376  : 8*4096*4    = 131072
//   Wt    @ 4456448  : 8*64*256*2  = 262144    bf16 [h][col][k]
//   numP  @ 4718592  : 4*128*8*32*64*4 = 33554432
//   denP  @ 38273024 : 4*128*8*32*4    = 524288
// total 38797312 B  (round-3 C=4 path needed 38.9 MB -> ws is big enough)
#define OFF_SRCP 4194304
#define OFF_DSTP 4325376
#define OFF_WT   4456448
#define OFF_NUMP 4718592
#define OFF_DENP 38273024ULL

// ---------------------------------------------------------------------------
// Prepack: Wt[hd][col][k] = (bf16) W[hd][k][col].
// ---------------------------------------------------------------------------
__global__ __launch_bounds__(256) void gat_prepack(
    const float* __restrict__ W, __bf16* __restrict__ Wt)
{
    int gid = blockIdx.x * 256 + threadIdx.x;   // 0..16383
    int hd  = gid >> 11;
    int rem = gid & 2047;
    int c   = rem >> 5;        // 0..63
    int kg  = rem & 31;        // 0..31 (groups of 8 k)
    const float* src = W + ((size_t)hd * IN_FEAT + kg * 8) * OUT_FEAT + c;
    bf16x8 v;
    #pragma unroll
    for (int t = 0; t < 8; ++t) v[t] = (__bf16)src[(size_t)t * OUT_FEAT];
    *(bf16x8*)(Wt + ((size_t)hd * OUT_FEAT + c) * IN_FEAT + kg * 8) = v;
}

// ---------------------------------------------------------------------------
// Phase 1: h = x @ W[h]; emits h_t (bf16, [h][feat][node]) + src/dst
// projections pre-scaled by log2(e). 512 blocks x 256 thr.
// __launch_bounds__(256,4): 128-VGPR budget so all 48 staging loads pipeline.
// ---------------------------------------------------------------------------
__global__ __launch_bounds__(256, 4) void gat_phase1(
    const float*  __restrict__ x,      // [4096][256]
    const __bf16* __restrict__ Wt,     // [8][64][256]
    const float*  __restrict__ a,      // [8][128]
    __bf16* __restrict__ h_t,
    float*  __restrict__ srcp,
    float*  __restrict__ dstp)
{
    const int lane = threadIdx.x & 63;
    const int wv   = threadIdx.x >> 6;
    const int gw   = blockIdx.x * 4 + wv;   // 0..2047
    const int hd   = gw & 7;
    const int tile = gw >> 3;               // 0..255
    const int r    = lane & 15;
    const int q    = lane >> 4;
    const int nb   = tile * 16;

    const float*  xrow = x  + (size_t)(nb + r) * IN_FEAT;
    const __bf16* Wth  = Wt + (size_t)hd * OUT_FEAT * IN_FEAT;

    f32x4 acc[4] = {};  // acc[f][reg] = h[nb + 4q + reg][16f + r]

    #pragma unroll
    for (int k0 = 0; k0 < IN_FEAT; k0 += 32) {
        float4 xa = *(const float4*)(xrow + k0 + q * 8);
        float4 xb = *(const float4*)(xrow + k0 + q * 8 + 4);
        bf16x8 af;
        af[0] = (__bf16)xa.x; af[1] = (__bf16)xa.y;
        af[2] = (__bf16)xa.z; af[3] = (__bf16)xa.w;
        af[4] = (__bf16)xb.x; af[5] = (__bf16)xb.y;
        af[6] = (__bf16)xb.z; af[7] = (__bf16)xb.w;
        #pragma unroll
        for (int f = 0; f < 4; ++f) {
            bf16x8 bf = *(const bf16x8*)(Wth + (size_t)(16 * f + r) * IN_FEAT + k0 + q * 8);
            acc[f] = __builtin_amdgcn_mfma_f32_16x16x32_bf16(af, bf, acc[f], 0, 0, 0);
        }
    }

    float asv[4], adv[4];
    #pragma unroll
    for (int f = 0; f < 4; ++f) {
        asv[f] = a[hd * 128 + 16 * f + r];
        adv[f] = a[hd * 128 + 64 + 16 * f + r];
    }
    float sp[4], dp[4];
    #pragma unroll
    for (int reg = 0; reg < 4; ++reg) {
        sp[reg] = acc[0][reg] * asv[0] + acc[1][reg] * asv[1]
                + acc[2][reg] * asv[2] + acc[3][reg] * asv[3];
        dp[reg] = acc[0][reg] * adv[0] + acc[1][reg] * adv[1]
                + acc[2][reg] * adv[2] + acc[3][reg] * adv[3];
    }
    #pragma unroll
    for (int m = 1; m <= 8; m <<= 1) {
        #pragma unroll
        for (int reg = 0; reg < 4; ++reg) {
            sp[reg] += __shfl_xor(sp[reg], m);
            dp[reg] += __shfl_xor(dp[reg], m);
        }
    }

    #pragma unroll
    for (int f = 0; f < 4; ++f)
        #pragma unroll
        for (int reg = 0; reg < 4; ++reg)
            h_t[(size_t)(hd * OUT_FEAT + 16 * f + r) * N_NODES + nb + 4 * q + reg] =
                (__bf16)acc[f][reg];

    if (r == 0) {
        #pragma unroll
        for (int reg = 0; reg < 4; ++reg) {
            int row = nb + 4 * q + reg;
            srcp[hd * N_NODES + row] = sp[reg] * LOG2E;
            dstp[hd * N_NODES + row] = dp[reg] * LOG2E;
        }
    }
}

// ---------------------------------------------------------------------------
// Phase 2 (partial): grid = 4 chunks x 128 rowblocks (32 rows). 512 thr,
// wave = head. Manual next-iter prefetch; __launch_bounds__(512,4) = 128 VGPR
// so ~10 loads stay in flight (round-3 bug: 32 VGPRs serialized every load).
// ---------------------------------------------------------------------------
#define MLEN 1024
__global__ __launch_bounds__(512, 4) void gat_phase2p(
    const __bf16* __restrict__ h_t,
    const float*  __restrict__ srcp,
    const float*  __restrict__ dstp,
    const int*    __restrict__ adj,
    float* __restrict__ numP,
    float* __restrict__ denP)
{
    const int lane   = threadIdx.x & 63;
    const int hd     = threadIdx.x >> 6;
    const int r      = lane & 15;
    const int q      = lane >> 4;
    const int rowblk = blockIdx.x & 127;
    const int chunk  = blockIdx.x >> 7;
    const int n0     = rowblk * 32;
    const int mbase  = chunk * MLEN;

    const float   srcv0 = srcp[hd * N_NODES + n0 + r];
    const float   srcv1 = srcp[hd * N_NODES + n0 + 16 + r];
    const float*  dsth  = dstp + (size_t)hd * N_NODES + mbase;
    const __bf16* Vh    = h_t + (size_t)hd * OUT_FEAT * N_NODES + mbase;
    const int*    adjr0 = adj + (size_t)(n0 + r) * N_NODES + mbase;
    const int*    adjr1 = adj + (size_t)(n0 + 16 + r) * N_NODES + mbase;

    f32x4 acc0 = {}, acc1 = {}, acc2 = {}, acc3 = {}, accD0 = {};
    f32x4 acc4 = {}, acc5 = {}, acc6 = {}, acc7 = {}, accD1 = {};
    bf16x8 ones;
    #pragma unroll
    for (int j = 0; j < 8; ++j) ones[j] = (__bf16)1.0f;

    const int qb = q * 8;

    // current-iteration register set (prefetched)
    float4 d0 = *(const float4*)(dsth + qb);
    float4 d1 = *(const float4*)(dsth + qb + 4);
    int4 A00 = *(const int4*)(adjr0 + qb);
    int4 A01 = *(const int4*)(adjr0 + qb + 4);
    int4 A10 = *(const int4*)(adjr1 + qb);
    int4 A11 = *(const int4*)(adjr1 + qb + 4);
    bf16x8 b0 = *(const bf16x8*)(Vh + (size_t)(r)      * N_NODES + qb);
    bf16x8 b1 = *(const bf16x8*)(Vh + (size_t)(16 + r) * N_NODES + qb);
    bf16x8 b2 = *(const bf16x8*)(Vh + (size_t)(32 + r) * N_NODES + qb);
    bf16x8 b3 = *(const bf16x8*)(Vh + (size_t)(48 + r) * N_NODES + qb);

    for (int m0 = 0; m0 < MLEN; m0 += 32) {
        // prefetch next iteration (wrap to a safe addr on the last iter)
        const int nxt = (m0 + 32 < MLEN) ? (m0 + 32 + qb) : qb;
        float4 nd0 = *(const float4*)(dsth + nxt);
        float4 nd1 = *(const float4*)(dsth + nxt + 4);
        int4 nA00 = *(const int4*)(adjr0 + nxt);
        int4 nA01 = *(const int4*)(adjr0 + nxt + 4);
        int4 nA10 = *(const int4*)(adjr1 + nxt);
        int4 nA11 = *(const int4*)(adjr1 + nxt + 4);
        bf16x8 nb0 = *(const bf16x8*)(Vh + (size_t)(r)      * N_NODES + nxt);
        bf16x8 nb1 = *(const bf16x8*)(Vh + (size_t)(16 + r) * N_NODES + nxt);
        bf16x8 nb2 = *(const bf16x8*)(Vh + (size_t)(32 + r) * N_NODES + nxt);
        bf16x8 nb3 = *(const bf16x8*)(Vh + (size_t)(48 + r) * N_NODES + nxt);

        // weights for the two 16-row sets
        float dv[8] = {d0.x, d0.y, d0.z, d0.w, d1.x, d1.y, d1.z, d1.w};
        int   a0[8] = {A00.x, A00.y, A00.z, A00.w, A01.x, A01.y, A01.z, A01.w};
        int   a1[8] = {A10.x, A10.y, A10.z, A10.w, A11.x, A11.y, A11.z, A11.w};
        bf16x8 af0, af1;
        #pragma unroll
        for (int j = 0; j < 8; ++j) {
            float t0 = srcv0 + dv[j];
            float e0 = fmaxf(t0, 0.2f * t0);
            float w0 = a0[j] ? exp2f(e0) : 0.0f;
            af0[j] = (__bf16)w0;
            float t1 = srcv1 + dv[j];
            float e1 = fmaxf(t1, 0.2f * t1);
            float w1 = a1[j] ? exp2f(e1) : 0.0f;
            af1[j] = (__bf16)w1;
        }

        acc0  = __builtin_amdgcn_mfma_f32_16x16x32_bf16(af0, b0,   acc0,  0, 0, 0);
        acc1  = __builtin_amdgcn_mfma_f32_16x16x32_bf16(af0, b1,   acc1,  0, 0, 0);
        acc2  = __builtin_amdgcn_mfma_f32_16x16x32_bf16(af0, b2,   acc2,  0, 0, 0);
        acc3  = __builtin_amdgcn_mfma_f32_16x16x32_bf16(af0, b3,   acc3,  0, 0, 0);
        accD0 = __builtin_amdgcn_mfma_f32_16x16x32_bf16(af0, ones, accD0, 0, 0, 0);
        acc4  = __builtin_amdgcn_mfma_f32_16x16x32_bf16(af1, b0,   acc4,  0, 0, 0);
        acc5  = __builtin_amdgcn_mfma_f32_16x16x32_bf16(af1, b1,   acc5,  0, 0, 0);
        acc6  = __builtin_amdgcn_mfma_f32_16x16x32_bf16(af1, b2,   acc6,  0, 0, 0);
        acc7  = __builtin_amdgcn_mfma_f32_16x16x32_bf16(af1, b3,   acc7,  0, 0, 0);
        accD1 = __builtin_amdgcn_mfma_f32_16x16x32_bf16(af1, ones, accD1, 0, 0, 0);

        d0 = nd0; d1 = nd1;
        A00 = nA00; A01 = nA01; A10 = nA10; A11 = nA11;
        b0 = nb0; b1 = nb1; b2 = nb2; b3 = nb3;
    }

    float* np = numP + (((size_t)(chunk * 128 + rowblk)) * NHEAD + hd) * (32 * 64);
    float* dp = denP + (((size_t)(chunk * 128 + rowblk)) * NHEAD + hd) * 32;
    #pragma unroll
    for (int reg = 0; reg < 4; ++reg) {
        int row = 4 * q + reg;
        np[row * 64 +  0 + r] = acc0[reg];
        np[row * 64 + 16 + r] = acc1[reg];
        np[row * 64 + 32 + r] = acc2[reg];
        np[row * 64 + 48 + r] = acc3[reg];
        np[(16 + row) * 64 +  0 + r] = acc4[reg];
        np[(16 + row) * 64 + 16 + r] = acc5[reg];
        np[(16 + row) * 64 + 32 + r] = acc6[reg];
        np[(16 + row) * 64 + 48 + r] = acc7[reg];
        if (r == 0) {
            dp[row]      = accD0[reg];
            dp[16 + row] = accD1[reg];
        }
    }
}

// ---------------------------------------------------------------------------
// Combine: sum 4 chunks, divide, mean heads, ELU. 512 blocks x 256 thr.
// ---------------------------------------------------------------------------
__global__ __launch_bounds__(256) void gat_combine(
    const float* __restrict__ numP,
    const float* __restrict__ denP,
    float* __restrict__ out)
{
    const int gid = blockIdx.x * 256 + threadIdx.x;   // 0..131071
    const int idx = gid * 2;
    const int row = idx >> 6;
    const int cp  = idx & 63;
    const int rb  = row >> 5;
    const int rr  = row & 31;

    float s0 = 0.f, s1 = 0.f;
    #pragma unroll
    for (int h = 0; h < NHEAD; ++h) {
        float n0 = 0.f, n1 = 0.f, den = 0.f;
        #pragma unroll
        for (int c = 0; c < 4; ++c) {
            size_t base = ((size_t)(c * 128 + rb)) * NHEAD + h;
            float2 v = *(const float2*)(numP + base * (32 * 64) + rr * 64 + cp);
            n0 += v.x; n1 += v.y;
            den += denP[base * 32 + rr];
        }
        float inv = 1.f / den;
        s0 += n0 * inv;
        s1 += n1 * inv;
    }
    s0 *= 0.125f; s1 *= 0.125f;
    float e0 = s0 > 0.f ? s0 : expm1f(s0);
    float e1 = s1 > 0.f ? s1 : expm1f(s1);
    float2 pk = {e0, e1};
    *(float2*)(out + (size_t)row * OUT_FEAT + cp) = pk;
}

// ---------------------------------------------------------------------------
extern "C" void kernel_launch(void* const* d_in, const int* in_sizes, int n_in,
                              void* d_out, int out_size, void* d_ws, size_t ws_size,
                              hipStream_t stream)
{
    const float* x   = (const float*)d_in[0];
    const int*   adj = (const int*)d_in[1];
    const float* W   = (const float*)d_in[2];
    const float* a   = (const float*)d_in[3];
    float* out = (float*)d_out;

    char* ws = (char*)d_ws;
    __bf16* h_t  = (__bf16*)ws;
    float*  srcp = (float*)(ws + OFF_SRCP);
    float*  dstp = (float*)(ws + OFF_DSTP);
    __bf16* Wt   = (__bf16*)(ws + OFF_WT);
    float*  numP = (float*)(ws + OFF_NUMP);
    float*  denP = (float*)(ws + OFF_DENP);

    gat_prepack<<<64, 256, 0, stream>>>(W, Wt);
    gat_phase1 <<<512, 256, 0, stream>>>(x, Wt, a, h_t, srcp, dstp);
    gat_phase2p<<<512, 512, 0, stream>>>(h_t, srcp, dstp, adj, numP, denP);
    gat_combine<<<512, 256, 0, stream>>>(numP, denP, out);
}

// Round 5
// 219.576 us; speedup vs baseline: 1.4721x; 1.0969x over previous
//
#include <hip/hip_runtime.h>
#include <hip/hip_bf16.h>
#include <cstdint>

#define N_NODES 4096
#define IN_FEAT 256
#define OUT_FEAT 64
#define NHEAD 8
#define LOG2E 1.4426950408889634f

typedef __bf16 bf16x8 __attribute__((ext_vector_type(8)));
typedef float  f32x4  __attribute__((ext_vector_type(4)));

// ws layout (bytes) — total 15,335,424 (well under the 38.8 MB proven in r3):
//   h_t  @ 0        : 8*64*4096*2 = 4194304   bf16 [h][feat][node]
//   srcp @ 4194304  : 8*4096*4    = 131072
//   dstp @ 4325376  : 8*4096*4    = 131072
//   Wt   @ 4456448  : 8*64*256*2  = 262144    bf16 [h][col][k]
//   bm   @ 4718592  : 4096*4*4*32 = 2097152   adj bitmask, swizzled
//   numA @ 6815744  : 4096*8*64*4 = 8388608   f32 atomic accumulators
//   denA @ 15204352 : 4096*8*4    = 131072
#define OFF_SRCP 4194304
#define OFF_DSTP 4325376
#define OFF_WT   4456448
#define OFF_BM   4718592
#define OFF_NUMA 6815744
#define OFF_DENA 15204352

// ---------------------------------------------------------------------------
// Pack adj (int32 0/1, 67 MB) -> 2 MB bitmask, swizzled so each phase2p lane
// reads its bits as contiguous words:
//   byte bm[row][chunk][q][i] = bits of adj[row][chunk*1024 + i*32 + q*8 .. +8]
// Thread = (row, t): reads 32 contiguous ints (fully coalesced), writes 4 B.
// ---------------------------------------------------------------------------
__global__ __launch_bounds__(512) void gat_pack(
    const int* __restrict__ adj, unsigned char* __restrict__ bm)
{
    int gid = blockIdx.x * 512 + threadIdx.x;   // 0..524287
    int row = gid >> 7;
    int t   = gid & 127;                        // m in [t*32, t*32+32)
    const int* p = adj + (size_t)row * N_NODES + t * 32;
    int v[32];
    #pragma unroll
    for (int k = 0; k < 8; ++k) {
        int4 x4 = *(const int4*)(p + k * 4);
        v[k*4+0] = x4.x; v[k*4+1] = x4.y; v[k*4+2] = x4.z; v[k*4+3] = x4.w;
    }
    int c = t >> 5;     // chunk
    int i = t & 31;     // iteration index within chunk
    #pragma unroll
    for (int q = 0; q < 4; ++q) {
        unsigned b = 0;
        #pragma unroll
        for (int j = 0; j < 8; ++j) b |= (v[q*8+j] ? 1u : 0u) << j;
        bm[(((size_t)row * 4 + c) * 4 + q) * 32 + i] = (unsigned char)b;
    }
}

// ---------------------------------------------------------------------------
// Prepack: Wt[hd][col][k] = (bf16) W[hd][k][col].
// ---------------------------------------------------------------------------
__global__ __launch_bounds__(256) void gat_prepack(
    const float* __restrict__ W, __bf16* __restrict__ Wt)
{
    int gid = blockIdx.x * 256 + threadIdx.x;   // 0..16383
    int hd  = gid >> 11;
    int rem = gid & 2047;
    int c   = rem >> 5;
    int kg  = rem & 31;
    const float* src = W + ((size_t)hd * IN_FEAT + kg * 8) * OUT_FEAT + c;
    bf16x8 v;
    #pragma unroll
    for (int t = 0; t < 8; ++t) v[t] = (__bf16)src[(size_t)t * OUT_FEAT];
    *(bf16x8*)(Wt + ((size_t)hd * OUT_FEAT + c) * IN_FEAT + kg * 8) = v;
}

static __device__ inline unsigned int pk2(float a, float b) {
    union { __bf16 h[2]; unsigned int u; } t;
    t.h[0] = (__bf16)a; t.h[1] = (__bf16)b; return t.u;
}

// ---------------------------------------------------------------------------
// Phase 1: h = x @ W[h]; emits h_t (bf16) + src/dst projections (*log2 e).
// 512 blocks x 256 thr, wave = (head, 16-row tile).
// unroll 2 (NOT full): full unroll demanded ~190 VGPRs of in-flight loads
// against a 128 budget -> scratch spills (the r2-r4 ~80us phase1 mystery).
// ---------------------------------------------------------------------------
__global__ __launch_bounds__(256, 4) void gat_phase1(
    const float*  __restrict__ x,      // [4096][256]
    const __bf16* __restrict__ Wt,     // [8][64][256]
    const float*  __restrict__ a,      // [8][128]
    __bf16* __restrict__ h_t,
    float*  __restrict__ srcp,
    float*  __restrict__ dstp)
{
    const int lane = threadIdx.x & 63;
    const int wv   = threadIdx.x >> 6;
    const int gw   = blockIdx.x * 4 + wv;
    const int hd   = gw & 7;
    const int tile = gw >> 3;
    const int r    = lane & 15;
    const int q    = lane >> 4;
    const int nb   = tile * 16;

    const float*  xrow = x  + (size_t)(nb + r) * IN_FEAT;
    const __bf16* Wth  = Wt + (size_t)hd * OUT_FEAT * IN_FEAT;

    f32x4 acc[4] = {};

    #pragma unroll 2
    for (int k0 = 0; k0 < IN_FEAT; k0 += 32) {
        float4 xa = *(const float4*)(xrow + k0 + q * 8);
        float4 xb = *(const float4*)(xrow + k0 + q * 8 + 4);
        bf16x8 af;
        af[0] = (__bf16)xa.x; af[1] = (__bf16)xa.y;
        af[2] = (__bf16)xa.z; af[3] = (__bf16)xa.w;
        af[4] = (__bf16)xb.x; af[5] = (__bf16)xb.y;
        af[6] = (__bf16)xb.z; af[7] = (__bf16)xb.w;
        #pragma unroll
        for (int f = 0; f < 4; ++f) {
            bf16x8 bf = *(const bf16x8*)(Wth + (size_t)(16 * f + r) * IN_FEAT + k0 + q * 8);
            acc[f] = __builtin_amdgcn_mfma_f32_16x16x32_bf16(af, bf, acc[f], 0, 0, 0);
        }
    }

    float asv[4], adv[4];
    #pragma unroll
    for (int f = 0; f < 4; ++f) {
        asv[f] = a[hd * 128 + 16 * f + r];
        adv[f] = a[hd * 128 + 64 + 16 * f + r];
    }
    float sp[4], dp[4];
    #pragma unroll
    for (int reg = 0; reg < 4; ++reg) {
        sp[reg] = acc[0][reg] * asv[0] + acc[1][reg] * asv[1]
                + acc[2][reg] * asv[2] + acc[3][reg] * asv[3];
        dp[reg] = acc[0][reg] * adv[0] + acc[1][reg] * adv[1]
                + acc[2][reg] * adv[2] + acc[3][reg] * adv[3];
    }
    #pragma unroll
    for (int m = 1; m <= 8; m <<= 1) {
        #pragma unroll
        for (int reg = 0; reg < 4; ++reg) {
            sp[reg] += __shfl_xor(sp[reg], m);
            dp[reg] += __shfl_xor(dp[reg], m);
        }
    }

    // packed 8-B stores: 4 consecutive nodes per (feat) row
    #pragma unroll
    for (int f = 0; f < 4; ++f) {
        uint2 st = { pk2(acc[f][0], acc[f][1]), pk2(acc[f][2], acc[f][3]) };
        *(uint2*)(h_t + (size_t)(hd * OUT_FEAT + 16 * f + r) * N_NODES + nb + 4 * q) = st;
    }

    if (r == 0) {
        #pragma unroll
        for (int reg = 0; reg < 4; ++reg) {
            int row = nb + 4 * q + reg;
            srcp[hd * N_NODES + row] = sp[reg] * LOG2E;
            dstp[hd * N_NODES + row] = dp[reg] * LOG2E;
        }
    }
}

// ---------------------------------------------------------------------------
// Phase 2: grid = 4 chunks x 128 rowblocks (32 rows), 512 thr (wave = head).
// adj comes from the L1-resident bitmask; V/dst prefetched one iter ahead.
// Results atomically accumulated into numA/denA (f32, zeroed by memset).
// ---------------------------------------------------------------------------
#define MLEN 1024
__global__ __launch_bounds__(512, 4) void gat_phase2p(
    const __bf16* __restrict__ h_t,
    const float*  __restrict__ srcp,
    const float*  __restrict__ dstp,
    const unsigned int* __restrict__ bm,
    float* __restrict__ numA,
    float* __restrict__ denA)
{
    const int lane   = threadIdx.x & 63;
    const int hd     = threadIdx.x >> 6;
    const int r      = lane & 15;
    const int q      = lane >> 4;
    const int rowblk = blockIdx.x & 127;
    const int chunk  = blockIdx.x >> 7;
    const int n0     = rowblk * 32;
    const int mbase  = chunk * MLEN;

    const float   srcv0 = srcp[hd * N_NODES + n0 + r];
    const float   srcv1 = srcp[hd * N_NODES + n0 + 16 + r];
    const float*  dsth  = dstp + (size_t)hd * N_NODES + mbase;
    const __bf16* Vh    = h_t + (size_t)hd * OUT_FEAT * N_NODES + mbase;
    const unsigned int* bmr0 = bm + (((size_t)(n0 + r)      * 4 + chunk) * 4 + q) * 8;
    const unsigned int* bmr1 = bm + (((size_t)(n0 + 16 + r) * 4 + chunk) * 4 + q) * 8;

    f32x4 acc0 = {}, acc1 = {}, acc2 = {}, acc3 = {}, accD0 = {};
    f32x4 acc4 = {}, acc5 = {}, acc6 = {}, acc7 = {}, accD1 = {};
    bf16x8 ones;
    #pragma unroll
    for (int j = 0; j < 8; ++j) ones[j] = (__bf16)1.0f;

    const int qb = q * 8;

    // prefetched current-iteration registers
    float4 d0 = *(const float4*)(dsth + qb);
    float4 d1 = *(const float4*)(dsth + qb + 4);
    bf16x8 b0 = *(const bf16x8*)(Vh + (size_t)(r)      * N_NODES + qb);
    bf16x8 b1 = *(const bf16x8*)(Vh + (size_t)(16 + r) * N_NODES + qb);
    bf16x8 b2 = *(const bf16x8*)(Vh + (size_t)(32 + r) * N_NODES + qb);
    bf16x8 b3 = *(const bf16x8*)(Vh + (size_t)(48 + r) * N_NODES + qb);
    unsigned int bw0 = bmr0[0];
    unsigned int bw1 = bmr1[0];

    for (int w = 0; w < 8; ++w) {
        // prefetch next word-group's bits
        unsigned int nbw0 = bmr0[(w + 1) & 7];
        unsigned int nbw1 = bmr1[(w + 1) & 7];
        #pragma unroll
        for (int ii = 0; ii < 4; ++ii) {
            const int m0  = (w * 4 + ii) * 32;
            const int nxt = (m0 + 32 < MLEN) ? (m0 + 32 + qb) : qb;
            float4 nd0 = *(const float4*)(dsth + nxt);
            float4 nd1 = *(const float4*)(dsth + nxt + 4);
            bf16x8 nb0 = *(const bf16x8*)(Vh + (size_t)(r)      * N_NODES + nxt);
            bf16x8 nb1 = *(const bf16x8*)(Vh + (size_t)(16 + r) * N_NODES + nxt);
            bf16x8 nb2 = *(const bf16x8*)(Vh + (size_t)(32 + r) * N_NODES + nxt);
            bf16x8 nb3 = *(const bf16x8*)(Vh + (size_t)(48 + r) * N_NODES + nxt);

            float dv[8] = {d0.x, d0.y, d0.z, d0.w, d1.x, d1.y, d1.z, d1.w};
            bf16x8 af0, af1;
            #pragma unroll
            for (int j = 0; j < 8; ++j) {
                float t0 = srcv0 + dv[j];
                float e0 = fmaxf(t0, 0.2f * t0);
                float w0 = (bw0 & (1u << (ii * 8 + j))) ? exp2f(e0) : 0.0f;
                af0[j] = (__bf16)w0;
                float t1 = srcv1 + dv[j];
                float e1 = fmaxf(t1, 0.2f * t1);
                float w1 = (bw1 & (1u << (ii * 8 + j))) ? exp2f(e1) : 0.0f;
                af1[j] = (__bf16)w1;
            }

            acc0  = __builtin_amdgcn_mfma_f32_16x16x32_bf16(af0, b0,   acc0,  0, 0, 0);
            acc1  = __builtin_amdgcn_mfma_f32_16x16x32_bf16(af0, b1,   acc1,  0, 0, 0);
            acc2  = __builtin_amdgcn_mfma_f32_16x16x32_bf16(af0, b2,   acc2,  0, 0, 0);
            acc3  = __builtin_amdgcn_mfma_f32_16x16x32_bf16(af0, b3,   acc3,  0, 0, 0);
            accD0 = __builtin_amdgcn_mfma_f32_16x16x32_bf16(af0, ones, accD0, 0, 0, 0);
            acc4  = __builtin_amdgcn_mfma_f32_16x16x32_bf16(af1, b0,   acc4,  0, 0, 0);
            acc5  = __builtin_amdgcn_mfma_f32_16x16x32_bf16(af1, b1,   acc5,  0, 0, 0);
            acc6  = __builtin_amdgcn_mfma_f32_16x16x32_bf16(af1, b2,   acc6,  0, 0, 0);
            acc7  = __builtin_amdgcn_mfma_f32_16x16x32_bf16(af1, b3,   acc7,  0, 0, 0);
            accD1 = __builtin_amdgcn_mfma_f32_16x16x32_bf16(af1, ones, accD1, 0, 0, 0);

            d0 = nd0; d1 = nd1;
            b0 = nb0; b1 = nb1; b2 = nb2; b3 = nb3;
        }
        bw0 = nbw0; bw1 = nbw1;
    }

    #pragma unroll
    for (int reg = 0; reg < 4; ++reg) {
        int row0 = n0 + 4 * q + reg;
        int row1 = row0 + 16;
        atomicAdd(&numA[((size_t)row0 * NHEAD + hd) * 64 +  0 + r], acc0[reg]);
        atomicAdd(&numA[((size_t)row0 * NHEAD + hd) * 64 + 16 + r], acc1[reg]);
        atomicAdd(&numA[((size_t)row0 * NHEAD + hd) * 64 + 32 + r], acc2[reg]);
        atomicAdd(&numA[((size_t)row0 * NHEAD + hd) * 64 + 48 + r], acc3[reg]);
        atomicAdd(&numA[((size_t)row1 * NHEAD + hd) * 64 +  0 + r], acc4[reg]);
        atomicAdd(&numA[((size_t)row1 * NHEAD + hd) * 64 + 16 + r], acc5[reg]);
        atomicAdd(&numA[((size_t)row1 * NHEAD + hd) * 64 + 32 + r], acc6[reg]);
        atomicAdd(&numA[((size_t)row1 * NHEAD + hd) * 64 + 48 + r], acc7[reg]);
        if (r == 0) {
            atomicAdd(&denA[(size_t)row0 * NHEAD + hd], accD0[reg]);
            atomicAdd(&denA[(size_t)row1 * NHEAD + hd], accD1[reg]);
        }
    }
}

// ---------------------------------------------------------------------------
// Combine: divide, mean over heads, ELU. 256 blocks x 512 thr (2 cols/thr).
// ---------------------------------------------------------------------------
__global__ __launch_bounds__(512) void gat_combine(
    const float* __restrict__ numA,
    const float* __restrict__ denA,
    float* __restrict__ out)
{
    int gid = blockIdx.x * 512 + threadIdx.x;   // 0..131071
    int row = gid >> 5;
    int cp  = (gid & 31) * 2;
    float s0 = 0.f, s1 = 0.f;
    #pragma unroll
    for (int h = 0; h < NHEAD; ++h) {
        float2 v = *(const float2*)(numA + ((size_t)row * NHEAD + h) * 64 + cp);
        float inv = 1.f / denA[(size_t)row * NHEAD + h];
        s0 += v.x * inv;
        s1 += v.y * inv;
    }
    s0 *= 0.125f; s1 *= 0.125f;
    float e0 = s0 > 0.f ? s0 : expm1f(s0);
    float e1 = s1 > 0.f ? s1 : expm1f(s1);
    float2 pk = {e0, e1};
    *(float2*)(out + (size_t)row * OUT_FEAT + cp) = pk;
}

// ---------------------------------------------------------------------------
extern "C" void kernel_launch(void* const* d_in, const int* in_sizes, int n_in,
                              void* d_out, int out_size, void* d_ws, size_t ws_size,
                              hipStream_t stream)
{
    const float* x   = (const float*)d_in[0];
    const int*   adj = (const int*)d_in[1];
    const float* W   = (const float*)d_in[2];
    const float* a   = (const float*)d_in[3];
    float* out = (float*)d_out;

    char* ws = (char*)d_ws;
    __bf16*        h_t  = (__bf16*)ws;
    float*         srcp = (float*)(ws + OFF_SRCP);
    float*         dstp = (float*)(ws + OFF_DSTP);
    __bf16*        Wt   = (__bf16*)(ws + OFF_WT);
    unsigned char* bmB  = (unsigned char*)(ws + OFF_BM);
    float*         numA = (float*)(ws + OFF_NUMA);
    float*         denA = (float*)(ws + OFF_DENA);

    hipMemsetAsync(ws + OFF_NUMA, 0, 8388608 + 131072, stream);
    gat_pack   <<<1024, 512, 0, stream>>>(adj, bmB);
    gat_prepack<<<64,   256, 0, stream>>>(W, Wt);
    gat_phase1 <<<512,  256, 0, stream>>>(x, Wt, a, h_t, srcp, dstp);
    gat_phase2p<<<512,  512, 0, stream>>>(h_t, srcp, dstp, (const unsigned int*)bmB,
                                          numA, denA);
    gat_combine<<<256,  512, 0, stream>>>(numA, denA, out);
}